// Round 4
// baseline (251.464 us; speedup 1.0000x reference)
//
#include <hip/hip_runtime.h>
#include <stdint.h>

#define HW 625              // 25*25
#define NROT 6
#define C_OUT 161
#define OUT_PER_B (C_OUT * HW)   // 100625
#define IN_PER_B  (128 * HW)     // 80000
#define NT 256
#define QF  20000           // floats per heavy quarter (32 channels * 625)
#define NF4 5000            // float4s per quarter
#define CST 629             // obs LDS copy stride; 629 % 4 == 1 -> conflict-free

__global__ __launch_bounds__(NT)
void env_embed(const float* __restrict__ sta, const float* __restrict__ dyn,
               const float* __restrict__ obst, const float* __restrict__ ocur,
               const float* __restrict__ omem, const float* __restrict__ pvis,
               const float* __restrict__ atgt, const float* __restrict__ ptgt,
               const float* __restrict__ lead, const float* __restrict__ foll,
               const int* __restrict__ rots, float* __restrict__ out, const int nb)
{
    const int bid = blockIdx.x;
    const int t = threadIdx.x;
    const int nheavy = 4 * nb;

    if (bid >= nheavy) {
        // ================= small channels 128..160, one block per batch =========
        const int b = bid - nheavy;
        const int rot = rots[b];             // block-uniform
        const int bHW = b * HW;
        float* const out_b = out + (size_t)b * OUT_PER_B;

        for (int p = t; p < HW; p += NT) {
            const float obs = omem[bHW + p];
            float* const ob = out_b + p;

            ob[128 * HW] = obst[bHW + p] * obs;
            ob[129 * HW] = ocur[bHW + p] * obs;
            ob[130 * HW] = obs * obs;
            ob[138 * HW] = lead[bHW + p] * obs;
            ob[139 * HW] = foll[bHW + p] * obs;

            float s_pv = 0.f, s_at = 0.f, s_pt = 0.f;
            #pragma unroll
            for (int r = 0; r < NROT; ++r) { // iterate SOURCE rotation
                const float pv = pvis[(b * NROT + r) * HW + p];
                const float at = atgt[(b * NROT + r) * HW + p];
                const float pt = ptgt[(b * NROT + r) * HW + p];
                s_pv += pv; s_at += at; s_pt += pt;
                int jj = r + rot; if (jj >= NROT) jj -= NROT;   // dest channel
                ob[(131 + jj) * HW] = pv * 0.5f * obs;
                ob[(140 + jj) * HW] = at * 0.5f * obs;
                ob[(146 + jj) * HW] = pt * obs;
            }
            ob[137 * HW] = s_pv * obs;
            ob[152 * HW] = s_at * 0.5f * obs;
            ob[153 * HW] = s_pt * obs;
            ob[154 * HW] = 1.0f;
            #pragma unroll
            for (int jj = 0; jj < NROT; ++jj)
                ob[(155 + jj) * HW] = (jj == rot) ? 1.0f : 0.0f;
        }
        return;
    }

    // ================= heavy channels: 4 blocks per batch, 32 channels each ====
    const int b = bid >> 2;
    const int j = bid & 3;

    __shared__ float lobs[4 * CST];          // 4 bank-shifted copies of obs plane
    for (int p = t; p < HW; p += NT) {
        const float v = omem[b * HW + p];
        lobs[p] = v; lobs[CST + p] = v; lobs[2 * CST + p] = v; lobs[3 * CST + p] = v;
    }
    __syncthreads();

    const float* const sb = sta + (size_t)b * IN_PER_B + j * QF;   // 16B-aligned
    const float* const db = dyn + (size_t)b * IN_PER_B + j * QF;
    float* const ob = out + (size_t)b * OUT_PER_B + j * QF;        // align mod4 = b%4
    const float* const L = lobs + ((t >> 3) & 3) * CST;
    const int amode = b & 3;                 // block-uniform store-alignment mode

#define OBS4(Q, O0, O1, O2, O3) {                                  \
        int qq = (Q);                                              \
        O0 = L[qq]; qq = (qq == HW - 1) ? 0 : qq + 1;              \
        O1 = L[qq]; qq = (qq == HW - 1) ? 0 : qq + 1;              \
        O2 = L[qq]; qq = (qq == HW - 1) ? 0 : qq + 1;              \
        O3 = L[qq]; }

#define STORE4(PO, R0, R1, R2, R3) {                               \
        if (amode == 0)       *(float4*)(PO) = make_float4(R0, R1, R2, R3); \
        else if (amode == 2) { *(float2*)(PO) = make_float2(R0, R1);        \
                               *(float2*)((PO) + 2) = make_float2(R2, R3); }\
        else { (PO)[0] = R0; (PO)[1] = R1; (PO)[2] = R2; (PO)[3] = R3; } }

#define COMPUTE_STORE(IDX, S4, D4) {                               \
        float o0, o1, o2, o3;                                      \
        OBS4((IDX) % HW, o0, o1, o2, o3);                          \
        const float r0 = (S4.x + D4.x) * o0, r1 = (S4.y + D4.y) * o1; \
        const float r2 = (S4.z + D4.z) * o2, r3 = (S4.w + D4.w) * o3; \
        STORE4(ob + (IDX), r0, r1, r2, r3); }

    int k = t;
    for (; k + 3 * NT < NF4; k += 4 * NT) {
        const int i0 = 4 * k, i1 = 4 * (k + NT), i2 = 4 * (k + 2 * NT), i3 = 4 * (k + 3 * NT);
        // issue all 8 global loads before any use (8KB/wave in flight)
        const float4 s0 = *(const float4*)(sb + i0);
        const float4 d0 = *(const float4*)(db + i0);
        const float4 s1 = *(const float4*)(sb + i1);
        const float4 d1 = *(const float4*)(db + i1);
        const float4 s2 = *(const float4*)(sb + i2);
        const float4 d2 = *(const float4*)(db + i2);
        const float4 s3 = *(const float4*)(sb + i3);
        const float4 d3 = *(const float4*)(db + i3);

        COMPUTE_STORE(i0, s0, d0);
        COMPUTE_STORE(i1, s1, d1);
        COMPUTE_STORE(i2, s2, d2);
        COMPUTE_STORE(i3, s3, d3);
    }
    for (; k < NF4; k += NT) {
        const int i0 = 4 * k;
        const float4 s0 = *(const float4*)(sb + i0);
        const float4 d0 = *(const float4*)(db + i0);
        COMPUTE_STORE(i0, s0, d0);
    }
#undef OBS4
#undef STORE4
#undef COMPUTE_STORE
}

extern "C" void kernel_launch(void* const* d_in, const int* in_sizes, int n_in,
                              void* d_out, int out_size, void* d_ws, size_t ws_size,
                              hipStream_t stream) {
    const float* sta  = (const float*)d_in[0];
    const float* dyn  = (const float*)d_in[1];
    const float* obst = (const float*)d_in[2];
    const float* ocur = (const float*)d_in[3];
    const float* omem = (const float*)d_in[4];
    const float* pvis = (const float*)d_in[5];
    const float* atgt = (const float*)d_in[6];
    const float* ptgt = (const float*)d_in[7];
    const float* lead = (const float*)d_in[8];
    const float* foll = (const float*)d_in[9];
    const int*   rots = (const int*)d_in[10];
    float* out = (float*)d_out;

    const int nb = in_sizes[10];             // batch count (1024)

    hipLaunchKernelGGL(env_embed, dim3(5 * nb), dim3(NT), 0, stream,
                       sta, dyn, obst, ocur, omem, pvis, atgt, ptgt,
                       lead, foll, rots, out, nb);
}